// Round 17
// baseline (1390.103 us; speedup 1.0000x reference)
//
#include <hip/hip_runtime.h>

// ---------------------------------------------------------------------------
// CrossAttention_83528523972835 — round 17: R16 base (best 1354us) + safe
// dispatch merges (re-applied now that norm_reduce variance is eliminated):
// patchify+posfill one dispatch (z=130), Wm transpose folded into QKV/Wo
// transpose (z=5), z_kernel grid-strided (2048 blocks). 15 -> 12 dispatches.
// ---------------------------------------------------------------------------

typedef unsigned short u16;
typedef short bf16x8 __attribute__((ext_vector_type(8)));
typedef unsigned short u16x8 __attribute__((ext_vector_type(8)));
typedef float f32x4 __attribute__((ext_vector_type(4)));

#define WAITV(N) asm volatile("s_waitcnt vmcnt(" #N ")" ::: "memory")

static __device__ __forceinline__ void barx() {
    asm volatile("" ::: "memory");
    __builtin_amdgcn_s_barrier();
    asm volatile("" ::: "memory");
}

static __device__ __forceinline__ u16 f2b(float f) {
    union { float f; unsigned int u; } cv; cv.f = f;
    unsigned int u = cv.u;
    unsigned int lsb = (u >> 16) & 1u;
    u += 0x7fffu + lsb;
    return (u16)(u >> 16);
}

static __device__ __forceinline__ float b2f(u16 u) {
    union { unsigned int i; float f; } c; c.i = ((unsigned int)u) << 16; return c.f;
}

// ---------------------------------------------------------------------------
// 4-window 256x256 GEMM body. K%128==0.
// ---------------------------------------------------------------------------
static __device__ __forceinline__ void gemm8p_body(
    const u16* __restrict__ A, const u16* __restrict__ Bt, void* __restrict__ Cv,
    const float* __restrict__ bias, int M, int N, int K,
    int lda, int ldb, int ldc, float alpha, int c_bf16, int row_remap,
    int m0, int n0, u16* lds)
{
    const int tid = threadIdx.x, lane = tid & 63, wave = tid >> 6;
    const int wm = wave >> 2, wn = wave & 3;      // 2M x 4N waves
    const int l15 = lane & 15, l4 = lane >> 4;
    const int scol = (((lane & 3) ^ ((lane >> 3) & 3)) << 3);
    const int bswz = ((l4 ^ ((l15 >> 1) & 3)) << 3);

    f32x4 acc[8][4] = {};
    const int nt = K >> 6;            // even, >= 4
    const int niter = nt >> 1;

    auto STAGE = [&](int tt, int kh, int isB) {
        const int c = tt & 1;
        const int k0 = (tt << 6) + (kh << 5);
        const int rbase = isB ? n0 : m0;
        const u16* P = isB ? Bt : A;
        const int ld = isB ? ldb : lda;
        const int lim = isB ? N : M;
        const int dbase = c * 32768 + isB * 16384 + kh * 8192;
        #pragma unroll
        for (int j = 0; j < 2; ++j) {
            const int r0 = j * 128 + wave * 16;
            int g = rbase + r0 + (lane >> 2); g = g < lim ? g : lim - 1;
            const u16* src = P + (long)g * ld + k0 + scol;
            __builtin_amdgcn_global_load_lds(
                (const __attribute__((address_space(1))) void*)src,
                (__attribute__((address_space(3))) void*)&lds[dbase + r0 * 32],
                16, 0, 0);
        }
    };

    bf16x8 bfr[4];
    auto LOADB = [&](int c, int kk) {
        #pragma unroll
        for (int nn = 0; nn < 4; ++nn) {
            const int row = wn * 64 + nn * 16 + l15;
            bfr[nn] = *(const bf16x8*)&lds[c * 32768 + 16384 + kk * 8192 + row * 32 + bswz];
        }
    };
    auto LDA = [&](int c, int kk, int mh, bf16x8* af) {
        #pragma unroll
        for (int mm = 0; mm < 4; ++mm) {
            const int row = wm * 128 + mh * 64 + mm * 16 + l15;
            af[mm] = *(const bf16x8*)&lds[c * 32768 + kk * 8192 + row * 32 + bswz];
        }
    };
    auto MM = [&](const bf16x8* af, int mh) {
        __builtin_amdgcn_s_setprio(1);
        #pragma unroll
        for (int mm = 0; mm < 4; ++mm)
            #pragma unroll
            for (int nn = 0; nn < 4; ++nn)
                acc[mh * 4 + mm][nn] = __builtin_amdgcn_mfma_f32_16x16x32_bf16(
                    af[mm], bfr[nn], acc[mh * 4 + mm][nn], 0, 0, 0);
        __builtin_amdgcn_s_setprio(0);
    };

    STAGE(0, 0, 0); STAGE(0, 0, 1); STAGE(0, 1, 0); STAGE(0, 1, 1);
    STAGE(1, 0, 0); STAGE(1, 0, 1);

    bf16x8 a0[4], a1[4];
    for (int i = 0; i < niter; ++i) {
        const int t0 = 2 * i, t1 = t0 + 1;
        const bool has2 = (t0 + 2 < nt);
        WAITV(8); barx();
        LOADB(0, 0); LDA(0, 0, 0, a0);
        STAGE(t1, 1, 0); STAGE(t1, 1, 1);
        MM(a0, 0); LDA(0, 0, 1, a1); MM(a1, 1);
        WAITV(8); barx();
        LOADB(0, 1); LDA(0, 1, 0, a0);
        if (has2) { STAGE(t0 + 2, 0, 0); STAGE(t0 + 2, 0, 1); }
        MM(a0, 0); LDA(0, 1, 1, a1); MM(a1, 1);
        if (has2) { WAITV(8); } else { WAITV(4); }
        barx();
        LOADB(1, 0); LDA(1, 0, 0, a0);
        if (has2) { STAGE(t0 + 2, 1, 0); STAGE(t0 + 2, 1, 1); }
        MM(a0, 0); LDA(1, 0, 1, a1); MM(a1, 1);
        if (has2) { WAITV(8); } else { WAITV(0); }
        barx();
        LOADB(1, 1); LDA(1, 1, 0, a0);
        if (has2) { STAGE(t1 + 2, 0, 0); STAGE(t1 + 2, 0, 1); }
        MM(a0, 0); LDA(1, 1, 1, a1); MM(a1, 1);
    }

    // epilogue: D map col=lane&15, row=4*(lane>>4)+reg  [m89-verified]
    #pragma unroll
    for (int mr = 0; mr < 8; ++mr) {
        #pragma unroll
        for (int nn = 0; nn < 4; ++nn) {
            const int col = n0 + wn * 64 + nn * 16 + l15;
            if (col >= N) continue;
            const float bv = bias ? bias[col] : 0.0f;
            #pragma unroll
            for (int jj = 0; jj < 4; ++jj) {
                const int row = m0 + wm * 128 + mr * 16 + l4 * 4 + jj;
                if (row >= M) continue;
                float v = alpha * acc[mr][nn][jj] + bv;
                long crow = row;
                if (row_remap) crow = (long)(row >> 6) * 129 + 65 + (row & 63);
                if (c_bf16) ((u16*)Cv)[crow * (long)ldc + col] = f2b(v);
                else        ((float*)Cv)[crow * (long)ldc + col] = v;
            }
        }
    }
}

__global__ __launch_bounds__(512, 2) void gemm_8p(
    const u16* __restrict__ A, const u16* __restrict__ Bt, void* __restrict__ Cv,
    const float* __restrict__ bias, int M, int N, int K,
    int lda, int ldb, int ldc, float alpha, int c_bf16, int row_remap)
{
    __shared__ u16 lds[65536];
    gemm8p_body(A, Bt, Cv, bias, M, N, K, lda, ldb, ldc, alpha, c_bf16, row_remap,
                blockIdx.x * 256, blockIdx.y * 256, lds);
}

// z-merged variant: per-z A/B/C/bias, bf16 outputs.
__global__ __launch_bounds__(512, 2) void gemm_8p3(
    const u16* A0, const u16* A1, const u16* A2,
    const u16* B0, const u16* B1, const u16* B2,
    u16* C0, u16* C1, u16* C2,
    const float* bias0, const float* bias1, const float* bias2,
    int M, int N, int K, int lda, int ldb, int ldc, float alpha, int row_remap)
{
    __shared__ u16 lds[65536];
    const int z = blockIdx.z;
    const u16* A = z == 0 ? A0 : (z == 1 ? A1 : A2);
    const u16* B = z == 0 ? B0 : (z == 1 ? B1 : B2);
    u16* C = z == 0 ? C0 : (z == 1 ? C1 : C2);
    const float* bias = z == 0 ? bias0 : (z == 1 ? bias1 : bias2);
    gemm8p_body(A, B, C, bias, M, N, K, lda, ldb, ldc, alpha, 1, row_remap,
                blockIdx.x * 256, blockIdx.y * 256, lds);
}

// ---------------------------------------------------------------------------
// Pipelined 128^2 bf16 GEMM (proj), persistent.
// ---------------------------------------------------------------------------
__global__ __launch_bounds__(256, 2) void gemm_pipe(
    const u16* __restrict__ A, const u16* __restrict__ Bt, void* __restrict__ Cv,
    const float* __restrict__ bias, int M, int N, int K,
    int lda, int ldb, int ldc, float alpha, int c_bf16)
{
    __shared__ u16 lds[2 * 16384];

    const int tid = threadIdx.x, lane = tid & 63, wave = tid >> 6;
    const int wm = wave >> 1, wn = wave & 1;
    const int l15 = lane & 15, l4 = lane >> 4;

    const int srow = tid >> 3;
    const int scol = (((tid & 7) * 16) ^ (((tid >> 3) & 7) << 4)) >> 1;
    const int cf0 = (((0 * 64) + l4 * 16) ^ ((l15 & 7) << 4)) >> 1;
    const int cf1 = (((1 * 64) + l4 * 16) ^ ((l15 & 7) << 4)) >> 1;

    const int nt = K >> 6;
    const int nbx = (M + 127) >> 7, nby = N >> 7;
    const int ntiles = nbx * nby;

    for (int tile = blockIdx.x; tile < ntiles; tile += gridDim.x) {
        const int m0 = (tile / nby) * 128, n0 = (tile % nby) * 128;

        auto STAGE = [&](int c, int t) {
            const int k0 = t << 6;
            #pragma unroll
            for (int j = 0; j < 4; ++j) {
                const int r = j * 32 + srow;
                int ga = m0 + r; ga = ga < M ? ga : M - 1;
                const u16* srcA = A + (long)ga * lda + k0 + scol;
                __builtin_amdgcn_global_load_lds(
                    (const __attribute__((address_space(1))) void*)srcA,
                    (__attribute__((address_space(3))) void*)&lds[c * 16384 + j * 2048 + wave * 512],
                    16, 0, 0);
                int gb = n0 + r; gb = gb < N ? gb : N - 1;
                const u16* srcB = Bt + (long)gb * ldb + k0 + scol;
                __builtin_amdgcn_global_load_lds(
                    (const __attribute__((address_space(1))) void*)srcB,
                    (__attribute__((address_space(3))) void*)&lds[c * 16384 + 8192 + j * 2048 + wave * 512],
                    16, 0, 0);
            }
        };

        f32x4 acc[4][4] = {};
        STAGE(0, 0);
        __syncthreads();
        for (int t = 0; t < nt; ++t) {
            const int c = t & 1;
            if (t + 1 < nt) STAGE(c ^ 1, t + 1);
            const int ab = c * 16384, bb = ab + 8192;
            #pragma unroll
            for (int kk = 0; kk < 2; ++kk) {
                const int cf = kk ? cf1 : cf0;
                bf16x8 af[4], bfr[4];
                #pragma unroll
                for (int m = 0; m < 4; ++m)
                    af[m] = *(const bf16x8*)&lds[ab + (wm * 64 + m * 16 + l15) * 64 + cf];
                #pragma unroll
                for (int n = 0; n < 4; ++n)
                    bfr[n] = *(const bf16x8*)&lds[bb + (wn * 64 + n * 16 + l15) * 64 + cf];
                __builtin_amdgcn_s_setprio(1);
                #pragma unroll
                for (int m = 0; m < 4; ++m)
                    #pragma unroll
                    for (int n = 0; n < 4; ++n)
                        acc[m][n] = __builtin_amdgcn_mfma_f32_16x16x32_bf16(
                            af[m], bfr[n], acc[m][n], 0, 0, 0);
                __builtin_amdgcn_s_setprio(0);
            }
            __syncthreads();
        }

        #pragma unroll
        for (int m = 0; m < 4; ++m) {
            #pragma unroll
            for (int n = 0; n < 4; ++n) {
                const int col = n0 + wn * 64 + n * 16 + l15;
                if (col >= N) continue;
                const float bv = bias ? bias[col] : 0.0f;
                #pragma unroll
                for (int j = 0; j < 4; ++j) {
                    const int row = m0 + wm * 64 + m * 16 + l4 * 4 + j;
                    if (row >= M) continue;
                    float v = alpha * acc[m][n][j] + bv;
                    if (c_bf16) ((u16*)Cv)[(long)row * ldc + col] = f2b(v);
                    else        ((float*)Cv)[(long)row * ldc + col] = v;
                }
            }
        }
    }
}

// ---------------------------------------------------------------------------
// Generic bf16 GEMM (batch): attn@v (batched K=144, M=128).
// ---------------------------------------------------------------------------
__global__ __launch_bounds__(256) void gemm_bt(
    const u16* __restrict__ A, const u16* __restrict__ Bt, void* __restrict__ Cv,
    const float* __restrict__ bias, int M, int N, int K,
    int lda, int ldb, int ldc, float alpha, int c_bf16, int row_remap,
    long sA, long sB, long sCo, long sCi, int binner)
{
    const int bz = blockIdx.z;
    const u16* Ab = A + (long)bz * sA;
    const u16* Bb = Bt + (long)bz * sB;
    const long cOff = (long)(bz / binner) * sCo + (long)(bz % binner) * sCi;

    __shared__ u16 As[128][72];
    __shared__ u16 Bs[128][72];

    const int tid = threadIdx.x;
    const int lane = tid & 63;
    const int wave = tid >> 6;
    const int wr = wave >> 1, wc = wave & 1;
    const int l15 = lane & 15, l4 = lane >> 4;
    const int m0 = blockIdx.x * 128, n0 = blockIdx.y * 128;

    const int r = tid >> 3;
    const int kof = (tid & 7) * 8;

    f32x4 acc[4][4] = {};

    const int ktiles = (K + 63) / 64;
    for (int kt = 0; kt < ktiles; ++kt) {
        const int k0 = kt * 64;
        __syncthreads();
        #pragma unroll
        for (int i = 0; i < 4; ++i) {
            const int row = r + 32 * i;
            const int gk = k0 + kof;
            u16x8 v = {0,0,0,0,0,0,0,0};
            const int grow = m0 + row;
            if (grow < M && gk < K)
                v = *(const u16x8*)(Ab + (long)grow * lda + gk);
            *(u16x8*)&As[row][kof] = v;
        }
        #pragma unroll
        for (int i = 0; i < 4; ++i) {
            const int row = r + 32 * i;
            const int gk = k0 + kof;
            u16x8 v = {0,0,0,0,0,0,0,0};
            const int gcol = n0 + row;
            if (gcol < N && gk < K)
                v = *(const u16x8*)(Bb + (long)gcol * ldb + gk);
            *(u16x8*)&Bs[row][kof] = v;
        }
        __syncthreads();
        #pragma unroll
        for (int ks = 0; ks < 2; ++ks) {
            bf16x8 af[4], bfr[4];
            #pragma unroll
            for (int m = 0; m < 4; ++m)
                af[m] = *(const bf16x8*)&As[wr*64 + m*16 + l15][ks*32 + l4*8];
            #pragma unroll
            for (int n = 0; n < 4; ++n)
                bfr[n] = *(const bf16x8*)&Bs[wc*64 + n*16 + l15][ks*32 + l4*8];
            #pragma unroll
            for (int m = 0; m < 4; ++m)
                #pragma unroll
                for (int n = 0; n < 4; ++n)
                    acc[m][n] = __builtin_amdgcn_mfma_f32_16x16x32_bf16(
                        af[m], bfr[n], acc[m][n], 0, 0, 0);
        }
    }

    #pragma unroll
    for (int m = 0; m < 4; ++m) {
        #pragma unroll
        for (int n = 0; n < 4; ++n) {
            const int col = n0 + wc*64 + n*16 + l15;
            if (col >= N) continue;
            const float bv = bias ? bias[col] : 0.0f;
            #pragma unroll
            for (int j = 0; j < 4; ++j) {
                const int row = m0 + wr*64 + m*16 + l4*4 + j;
                if (row >= M) continue;
                float v = alpha * acc[m][n][j] + bv;
                long crow = row;
                if (row_remap) crow = (long)(row >> 6) * 129 + 65 + (row & 63);
                if (c_bf16) ((u16*)Cv)[cOff + crow * (long)ldc + col] = f2b(v);
                else        ((float*)Cv)[cOff + crow * (long)ldc + col] = v;
            }
        }
    }
}

// ---------------------------------------------------------------------------
// Fused dots + softmax, persistent over 516 row-groups (grid 512).
// ---------------------------------------------------------------------------
__global__ __launch_bounds__(256, 2) void fdots_kernel(
    const u16* __restrict__ z, const u16* __restrict__ Wm_t,
    const float* __restrict__ bm, u16* __restrict__ attn)
{
    __shared__ u16 wlds[144 * 264];
    const int tid = threadIdx.x;
    for (int i = tid; i < 144 * 32; i += 256) {
        const int row = i >> 5, c8 = i & 31;
        *(u16x8*)&wlds[row * 264 + c8 * 8] = *(const u16x8*)&Wm_t[row * 256 + c8 * 8];
    }
    __syncthreads();
    const int lane = tid & 63, wave = tid >> 6;
    const int l15 = lane & 15, l4 = lane >> 4;

    float bmv[9];
    #pragma unroll
    for (int c = 0; c < 9; ++c) {
        const int col = c * 16 + l15;
        bmv[c] = (col < 129) ? bm[col] : 0.0f;
    }

    for (int rg = blockIdx.x; rg < 516; rg += gridDim.x) {
        const long rowbase = (long)rg * 128 + wave * 32;

        f32x4 acc[2][9] = {};
        #pragma unroll
        for (int kk = 0; kk < 8; ++kk) {
            bf16x8 af[2];
            #pragma unroll
            for (int rgp = 0; rgp < 2; ++rgp)
                af[rgp] = *(const bf16x8*)&z[(rowbase + rgp * 16 + l15) * 256 + kk * 32 + l4 * 8];
            #pragma unroll
            for (int c = 0; c < 9; ++c) {
                const bf16x8 bf = *(const bf16x8*)&wlds[(c * 16 + l15) * 264 + kk * 32 + l4 * 8];
                #pragma unroll
                for (int rgp = 0; rgp < 2; ++rgp)
                    acc[rgp][c] = __builtin_amdgcn_mfma_f32_16x16x32_bf16(af[rgp], bf, acc[rgp][c], 0, 0, 0);
            }
        }

        #pragma unroll
        for (int rgp = 0; rgp < 2; ++rgp) {
            #pragma unroll
            for (int j = 0; j < 4; ++j) {
                float v[9]; float mx = -1e30f;
                #pragma unroll
                for (int c = 0; c < 9; ++c) {
                    const int col = c * 16 + l15;
                    v[c] = (col < 129) ? (0.0625f * acc[rgp][c][j] + bmv[c]) : -1e30f;
                    mx = fmaxf(mx, v[c]);
                }
                #pragma unroll
                for (int o = 1; o < 16; o <<= 1) mx = fmaxf(mx, __shfl_xor(mx, o, 64));
                float s = 0.f;
                #pragma unroll
                for (int c = 0; c < 9; ++c) {
                    v[c] = (c * 16 + l15 < 129) ? expf(v[c] - mx) : 0.0f;
                    s += v[c];
                }
                #pragma unroll
                for (int o = 1; o < 16; o <<= 1) s += __shfl_xor(s, o, 64);
                const float inv = 1.0f / s;
                u16* ar = attn + (rowbase + rgp * 16 + l4 * 4 + j) * 144;
                #pragma unroll
                for (int c = 0; c < 9; ++c)
                    ar[c * 16 + l15] = f2b(v[c] * inv);
            }
        }
    }
}

// out row n=128 per (b,h)
__global__ __launch_bounds__(256) void row128_kernel(
    const u16* __restrict__ attn, const u16* __restrict__ v_t, u16* __restrict__ outm)
{
    const int bh = blockIdx.x, d = threadIdx.x;
    const int b = bh >> 3, h = bh & 7;
    __shared__ float a[144];
    for (int j = threadIdx.x; j < 144; j += 256)
        a[j] = (j < 129) ? b2f(attn[((long)bh * 129 + 128) * 144 + j]) : 0.0f;
    __syncthreads();
    const u16* vr = v_t + ((long)bh * 256 + d) * 144;
    float s = 0.f;
    #pragma unroll
    for (int j8 = 0; j8 < 18; ++j8) {
        const bf16x8 vv = *(const bf16x8*)&vr[j8 * 8];
        #pragma unroll
        for (int e = 0; e < 8; ++e) s += a[j8 * 8 + e] * b2f((u16)vv[e]);
    }
    outm[((long)(b * 129 + 128)) * 2048 + h * 256 + d] = f2b(s);
}

// transpose + f32->bf16, z-selectable (up to 5-way; z==4 has its own shape)
__global__ __launch_bounds__(256) void transpose_conv5(
    const float* in0, const float* in1, const float* in2, const float* in3,
    const float* in4,
    u16* o0, u16* o1, u16* o2, u16* o3, u16* o4,
    int K, int N, int KP, int NPd,
    int K4, int N4, int KP4, int NP4)
{
    const int zz = blockIdx.z;
    const float* in = zz == 0 ? in0 : (zz == 1 ? in1 : (zz == 2 ? in2 :
                      (zz == 3 ? in3 : in4)));
    u16* out = zz == 0 ? o0 : (zz == 1 ? o1 : (zz == 2 ? o2 :
               (zz == 3 ? o3 : o4)));
    if (zz == 4) { K = K4; N = N4; KP = KP4; NPd = NP4; }
    __shared__ float tile[32][33];
    const int k0 = blockIdx.x * 32, n0 = blockIdx.y * 32;
    const int tx = threadIdx.x & 31, ty = threadIdx.x >> 5;   // 32x8
    if (k0 >= KP || n0 >= NPd) return;
    #pragma unroll
    for (int i = 0; i < 4; ++i) {
        const int k = k0 + ty + i*8, n = n0 + tx;
        tile[ty + i*8][tx] = (k < K && n < N) ? in[(long)k * N + n] : 0.0f;
    }
    __syncthreads();
    #pragma unroll
    for (int i = 0; i < 4; ++i) {
        const int n = n0 + ty + i*8, k = k0 + tx;
        if (n < NPd && k < KP) out[(long)n * KP + k] = f2b(tile[tx][ty + i*8]);
    }
}

// patchify (z<128) + posfill (z in [128,130)).
__global__ __launch_bounds__(256) void patchify_kernel(
    const float* __restrict__ xq, const float* __restrict__ xkv,
    u16* __restrict__ oq, u16* __restrict__ okv,
    const float* __restrict__ pos, u16* __restrict__ Tq, u16* __restrict__ Tk)
{
    const int zz = blockIdx.z;
    if (zz >= 128) {
        const int blk = (zz - 128) * 16 + blockIdx.y * 2 + blockIdx.x; // 0..31
        const int stride = 32 * 256;
        for (int idx = blk * 256 + threadIdx.x; idx < 65 * 64 * 256; idx += stride) {
            const int c8 = idx & 255;
            const int tb = idx >> 8;
            const int t = tb >> 6, b = tb & 63;
            const float* pr = pos + (long)t * 2048 + c8 * 8;
            u16x8 v;
            #pragma unroll
            for (int e = 0; e < 8; ++e) v[e] = f2b(pr[e]);
            const long o = ((long)b * 129 + t) * 2048 + c8 * 8;
            *(u16x8*)&Tq[o] = v;
            *(u16x8*)&Tk[o] = v;
        }
        return;
    }
    __shared__ u16 tile[64 * 7 * 58];
    const float* x = (zz >= 64) ? xkv : xq;
    u16* out = (zz >= 64) ? okv : oq;
    const int b = zz & 63, hh = blockIdx.y, cg = blockIdx.x;
    const int c0 = cg * 64;
    for (int i = threadIdx.x; i < 64 * 392; i += 256) {
        const int c = i / 392, rem = i - c * 392;
        const int p1 = rem / 56, w = rem - p1 * 56;
        const float v = x[(((long)b * 128 + c0 + c) * 56 + hh * 7 + p1) * 56 + w];
        tile[(c * 7 + p1) * 58 + w] = f2b(v);
    }
    __syncthreads();
    #pragma unroll
    for (int ww = 0; ww < 8; ++ww) {
        const long base = ((long)(b * 64 + hh * 8 + ww)) * 6272 + c0;
        for (int j = threadIdx.x; j < 49 * 64; j += 256) {
            const int c = j & 63, pp = j >> 6;
            const int p1 = pp / 7, p2 = pp - p1 * 7;
            out[base + pp * 128 + c] = tile[(c * 7 + p1) * 58 + ww * 7 + p2];
        }
    }
}

// v_t[bh][d][n (pad 144)] = vmat[(b*129+n)*2048 + h*256 + d]; pads zeroed
__global__ void vtrans_kernel(const u16* __restrict__ vmat, u16* __restrict__ v_t)
{
    const int bh = blockIdx.z; const int b = bh >> 3, h = bh & 7;
    const int d0 = blockIdx.x * 32, n0 = blockIdx.y * 32;
    __shared__ u16 tile[32][33];
    const int tx = threadIdx.x, ty = threadIdx.y;   // (32,8)
    #pragma unroll
    for (int i = 0; i < 4; ++i) {
        const int n = n0 + ty + i*8;
        if (n < 129)
            tile[ty + i*8][tx] = vmat[((long)b*129 + n) * 2048 + h*256 + d0 + tx];
    }
    __syncthreads();
    #pragma unroll
    for (int i = 0; i < 4; ++i) {
        const int d = d0 + ty + i*8, n = n0 + tx;
        if (n < 144)
            v_t[((long)bh * 256 + d) * 144 + n] = (n < 129) ? tile[tx][ty + i*8] : (u16)0;
    }
}

// --------------------- threefry2x32, partitionable path --------------------
static __device__ __forceinline__ unsigned int rotl32(unsigned int x, int d) {
    return (x << d) | (x >> (32 - d));
}

static __device__ __forceinline__ float threefry_normal(unsigned int i) {
    const unsigned int ks0 = 0u, ks1 = 42u;
    const unsigned int ks2 = ks0 ^ ks1 ^ 0x1BD11BDAu;
    unsigned int x0 = 0u + ks0;
    unsigned int x1 = i + ks1;
#define TF_R(rr) { x0 += x1; x1 = rotl32(x1, rr); x1 ^= x0; }
    TF_R(13) TF_R(15) TF_R(26) TF_R(6)
    x0 += ks1; x1 += ks2 + 1u;
    TF_R(17) TF_R(29) TF_R(16) TF_R(24)
    x0 += ks2; x1 += ks0 + 2u;
    TF_R(13) TF_R(15) TF_R(26) TF_R(6)
    x0 += ks0; x1 += ks1 + 3u;
    TF_R(17) TF_R(29) TF_R(16) TF_R(24)
    x0 += ks1; x1 += ks2 + 4u;
    TF_R(13) TF_R(15) TF_R(26) TF_R(6)
    x0 += ks2; x1 += ks0 + 5u;
#undef TF_R
    const unsigned int bits = x0 ^ x1;
    const unsigned int fb = (bits >> 9) | 0x3f800000u;
    union { unsigned int u; float f; } cv; cv.u = fb;
    const float f = cv.f - 1.0f;
    const float lo = -0.99999994f;
    float u = f * (1.0f - lo) + lo;
    u = fmaxf(lo, u);
    return 1.4142135623730951f * erfinvf(u);
}

// fused: z = k + exp(0.5 q) * eps (bf16), outq = q/||q||, outk = k/||k||.
// grid-strided (2048 blocks).
__global__ __launch_bounds__(256) void z_kernel(
    const u16* __restrict__ qmat, const u16* __restrict__ kmat,
    const float* __restrict__ norms, u16* __restrict__ z,
    float* __restrict__ outq, float* __restrict__ outk)
{
    const unsigned int stride = gridDim.x * 256u;
    for (unsigned int i = blockIdx.x * 256u + threadIdx.x; i < 16908288u; i += stride) {
        const int d = i & 255; const unsigned int t = i >> 8;
        const int n = t % 129; const int bh = t / 129;
        const int b = bh >> 3, h = bh & 7;
        const long src = ((long)(b * 129 + n)) * 2048 + h * 256 + d;
        const float qf = b2f(qmat[src]);
        const float kf = b2f(kmat[src]);
        const float eps = threefry_normal(i);
        z[i] = f2b(kf + expf(0.5f * qf) * eps);
        outq[i] = qf / norms[b];
        outk[i] = kf / norms[64 + b];
    }
}

// LayerNorm row of proj[8256][2048] (bf16) -> ln bf16
__global__ __launch_bounds__(256) void ln_kernel(
    const u16* __restrict__ proj, const float* __restrict__ gamma,
    const float* __restrict__ beta, u16* __restrict__ ln)
{
    const int row = blockIdx.x;
    const u16* p = proj + (long)row * 2048;
    const int tid = threadIdx.x;
    float v[8]; float s = 0.f, s2 = 0.f;
    #pragma unroll
    for (int i = 0; i < 8; ++i) {
        v[i] = b2f(p[tid + i * 256]); s += v[i]; s2 += v[i] * v[i];
    }
    #pragma unroll
    for (int o = 32; o > 0; o >>= 1) { s += __shfl_down(s, o, 64); s2 += __shfl_down(s2, o, 64); }
    __shared__ float sh[8];
    if ((tid & 63) == 0) { sh[tid >> 6] = s; sh[4 + (tid >> 6)] = s2; }
    __syncthreads();
    s = sh[0] + sh[1] + sh[2] + sh[3];
    s2 = sh[4] + sh[5] + sh[6] + sh[7];
    const float mu = s * (1.0f / 2048.0f);
    const float var = s2 * (1.0f / 2048.0f) - mu * mu;
    const float rinv = 1.0f / sqrtf(var + 1e-5f);
    u16* lr = ln + (long)row * 2048;
    #pragma unroll
    for (int i = 0; i < 8; ++i) {
        const int c = tid + i * 256;
        lr[c] = f2b((v[i] - mu) * rinv * gamma[c] + beta[c]);
    }
}

// ---------------------------------------------------------------------------
// Two-stage L2 norms, deterministic (no atomics).
// ---------------------------------------------------------------------------
__global__ __launch_bounds__(256) void norm_partial(
    const u16* __restrict__ qmat, const u16* __restrict__ kmat,
    float* __restrict__ part)
{
    const int blk = blockIdx.x;               // 0..2047
    const int p = blk >> 4, sub = blk & 15;   // p: 0..127 (q:0-63, k:64-127)
    const int b = p & 63;
    const u16* src = (p >= 64 ? kmat : qmat) + (long)b * 264192 + sub * 16512;
    float s = 0.f;
    for (int i = threadIdx.x; i < 2064; i += 256) {       // 2064 x 8 = 16512
        const bf16x8 v = *(const bf16x8*)&src[i * 8];
        #pragma unroll
        for (int e = 0; e < 8; ++e) { const float x = b2f((u16)v[e]); s += x * x; }
    }
    #pragma unroll
    for (int o = 32; o > 0; o >>= 1) s += __shfl_down(s, o, 64);
    __shared__ float sh[4];
    if ((threadIdx.x & 63) == 0) sh[threadIdx.x >> 6] = s;
    __syncthreads();
    if (threadIdx.x == 0) part[blk] = sh[0] + sh[1] + sh[2] + sh[3];
}

__global__ void norm_final(const float* __restrict__ part, float* __restrict__ norms)
{
    const int p = threadIdx.x;                // 128 threads
    float s = 0.f;
    #pragma unroll
    for (int j = 0; j < 16; ++j) s += part[p * 16 + j];
    norms[p] = sqrtf(s);
}

// ---------------------------------------------------------------------------
extern "C" void kernel_launch(void* const* d_in, const int* in_sizes, int n_in,
                              void* d_out, int out_size, void* d_ws, size_t ws_size,
                              hipStream_t stream)
{
    const float* x_q   = (const float*)d_in[0];
    const float* x_kv  = (const float*)d_in[1];
    const float* W_ex  = (const float*)d_in[2];
    const float* b_ex  = (const float*)d_in[3];
    const float* W_en  = (const float*)d_in[4];
    const float* b_en  = (const float*)d_in[5];
    const float* pos   = (const float*)d_in[6];
    const float* Wq    = (const float*)d_in[7];
    const float* Wk    = (const float*)d_in[8];
    const float* Wv    = (const float*)d_in[9];
    const float* Wo    = (const float*)d_in[10];
    const float* bo    = (const float*)d_in[11];
    const float* gamma = (const float*)d_in[12];
    const float* beta  = (const float*)d_in[13];
    const float* Wh    = (const float*)d_in[14];
    const float* bh    = (const float*)d_in[15];
    const float* Wm    = (const float*)d_in[16];
    const float* bm    = (const float*)d_in[17];
    (void)in_sizes; (void)n_in; (void)out_size; (void)ws_size;

    char* ws = (char*)d_ws;
    size_t off = 0;
    auto alloc = [&](size_t bytes) -> char* {
        char* p = ws + off;
        off += (bytes + 255) & ~(size_t)255;
        return p;
    };
    u16*   Xq_p  = (u16*)alloc(4096UL * 6272 * 2);
    u16*   Xk_p  = (u16*)alloc(4096UL * 6272 * 2);
    u16*   Wex_t = (u16*)alloc(2048UL * 6272 * 2);
    u16*   Wen_t = (u16*)alloc(2048UL * 6272 * 2);
    u16*   Tq    = (u16*)alloc(8256UL * 2048 * 2);
    u16*   Tk    = (u16*)alloc(8256UL * 2048 * 2);
    u16*   Wq_t  = (u16*)alloc(2048UL * 2048 * 2);
    u16*   Wk_t  = (u16*)alloc(2048UL * 2048 * 2);
    u16*   Wv_t  = (u16*)alloc(2048UL * 2048 * 2);
    u16*   qmat  = (u16*)alloc(8256UL * 2048 * 2);
    u16*   kmat  = (u16*)alloc(8256UL * 2048 * 2);
    u16*   vmat  = (u16*)alloc(8256UL * 2048 * 2);
    u16*   v_t   = (u16*)alloc(512UL * 256 * 144 * 2);
    u16*   z     = (u16*)alloc(66048UL * 256 * 2);
    u16*   attn  = (u16*)alloc(66048UL * 144 * 2);
    u16*   outm  = (u16*)alloc(8256UL * 2048 * 2);
    u16*   proj  = (u16*)alloc(8256UL * 2048 * 2);
    u16*   ln    = (u16*)alloc(8256UL * 2048 * 2);
    u16*   Wo_t  = (u16*)alloc(2048UL * 2048 * 2);
    u16*   Wh_t  = (u16*)alloc(6272UL * 2048 * 2);
    u16*   Wm_t  = (u16*)alloc(144UL * 256 * 2);
    float* norms = (float*)alloc(128UL * 4);
    float* part  = (float*)alloc(2048UL * 4);

    // s1: embed transposes + patchify/posfill (merged)
    transpose_conv5<<<dim3(196, 64, 2), 256, 0, stream>>>(
        W_ex, W_en, W_ex, W_en, W_ex,
        Wex_t, Wen_t, Wex_t, Wen_t, Wex_t, 6272, 2048, 6272, 2048,
        6272, 2048, 6272, 2048);
    patchify_kernel<<<dim3(2, 8, 130), 256, 0, stream>>>(
        x_q, x_kv, Xq_p, Xk_p, pos, Tq, Tk);

    // s2: merged embed GEMMs (z=2): 256 blocks
    gemm_8p3<<<dim3(16, 8, 2), 512, 0, stream>>>(
        Xq_p, Xk_p, Xk_p, Wex_t, Wen_t, Wen_t, Tq, Tk, Tk,
        b_ex, b_en, b_en, 4096, 2048, 6272, 6272, 6272, 2048, 1.0f, 1);

    // s3: QKV+Wo+Wm transposes (z=5) + merged QKV GEMM (z=3, bf16)
    transpose_conv5<<<dim3(64, 64, 5), 256, 0, stream>>>(
        Wq, Wk, Wv, Wo, Wm,
        Wq_t, Wk_t, Wv_t, Wo_t, Wm_t, 2048, 2048, 2048, 2048,
        256, 129, 256, 144);
    gemm_8p3<<<dim3(33, 8, 3), 512, 0, stream>>>(
        Tq, Tk, Tk, Wq_t, Wk_t, Wv_t, qmat, kmat, vmat,
        nullptr, nullptr, nullptr, 8256, 2048, 2048, 2048, 2048, 2048, 1.0f, 0);

    // s4: v transpose -> v_t [bh][d][n pad144]
    vtrans_kernel<<<dim3(8, 5, 512), dim3(32, 8), 0, stream>>>(vmat, v_t);

    // s5: two-stage norms then fused reparam + qn/kn outputs
    norm_partial<<<2048, 256, 0, stream>>>(qmat, kmat, part);
    norm_final<<<1, 128, 0, stream>>>(part, norms);
    {
        float* outq = (float*)d_out + 51781632L;
        float* outk = outq + 16908288L;
        z_kernel<<<2048, 256, 0, stream>>>(qmat, kmat, norms, z, outq, outk);
    }

    // s6: fused dots+softmax -> attn bf16 (persistent, 512 blocks)
    fdots_kernel<<<512, 256, 0, stream>>>(z, Wm_t, bm, attn);

    // s7: attn @ v (batched bh=512, M=128) + row-128 kernel
    {
        dim3 grid(1, 2, 512);
        gemm_bt<<<grid, 256, 0, stream>>>(attn, v_t, outm, nullptr,
            128, 256, 144, 144, 144, 2048, 1.0f, 1, 0,
            129L * 144, 256L * 144, 129L * 2048, 256L, 8);
    }
    row128_kernel<<<512, 256, 0, stream>>>(attn, v_t, outm);

    // s8: proj GEMM (persistent gemm_pipe, bf16 out)
    gemm_pipe<<<1024, 256, 0, stream>>>(
        outm, Wo_t, proj, bo, 8256, 2048, 2048, 2048, 2048, 2048, 1.0f, 1);

    // s9: LayerNorm (bf16 in) -> ln bf16
    ln_kernel<<<8256, 256, 0, stream>>>(proj, gamma, beta, ln);

    // s10: Wh transpose + head GEMM (8p) -> d_out[0 : 51,781,632] f32
    transpose_conv5<<<dim3(64, 196, 1), 256, 0, stream>>>(
        Wh, Wh, Wh, Wh, Wh,
        Wh_t, Wh_t, Wh_t, Wh_t, Wh_t, 2048, 6272, 2048, 6272,
        2048, 6272, 2048, 6272);
    gemm_8p<<<dim3(33, 25), 512, 0, stream>>>(
        ln, Wh_t, (float*)d_out, bh, 8256, 6272, 2048, 2048, 2048, 6272, 1.0f, 0, 0);
}

// Round 18
// 1346.970 us; speedup vs baseline: 1.0320x; 1.0320x over previous
//
#include <hip/hip_runtime.h>

// ---------------------------------------------------------------------------
// CrossAttention_83528523972835 — round 18: FINAL. Exact resubmission of R16
// (best measured: 1354us). R17's dispatch merges regressed (-36us) and are
// reverted. Session summary: 3027us (first pass) -> 1354us via 8-phase 256^2
// MFMA GEMMs (T1-T5), fused dots+softmax, fused reparam+qn/kn, two-stage
// vectorized norms, coalesced patchify, bf16 intermediate precision.
// ---------------------------------------------------------------------------

typedef unsigned short u16;
typedef short bf16x8 __attribute__((ext_vector_type(8)));
typedef unsigned short u16x8 __attribute__((ext_vector_type(8)));
typedef float f32x4 __attribute__((ext_vector_type(4)));

#define WAITV(N) asm volatile("s_waitcnt vmcnt(" #N ")" ::: "memory")

static __device__ __forceinline__ void barx() {
    asm volatile("" ::: "memory");
    __builtin_amdgcn_s_barrier();
    asm volatile("" ::: "memory");
}

static __device__ __forceinline__ u16 f2b(float f) {
    union { float f; unsigned int u; } cv; cv.f = f;
    unsigned int u = cv.u;
    unsigned int lsb = (u >> 16) & 1u;
    u += 0x7fffu + lsb;
    return (u16)(u >> 16);
}

static __device__ __forceinline__ float b2f(u16 u) {
    union { unsigned int i; float f; } c; c.i = ((unsigned int)u) << 16; return c.f;
}

// ---------------------------------------------------------------------------
// 4-window 256x256 GEMM body. K%128==0.
// ---------------------------------------------------------------------------
static __device__ __forceinline__ void gemm8p_body(
    const u16* __restrict__ A, const u16* __restrict__ Bt, void* __restrict__ Cv,
    const float* __restrict__ bias, int M, int N, int K,
    int lda, int ldb, int ldc, float alpha, int c_bf16, int row_remap,
    int m0, int n0, u16* lds)
{
    const int tid = threadIdx.x, lane = tid & 63, wave = tid >> 6;
    const int wm = wave >> 2, wn = wave & 3;      // 2M x 4N waves
    const int l15 = lane & 15, l4 = lane >> 4;
    const int scol = (((lane & 3) ^ ((lane >> 3) & 3)) << 3);
    const int bswz = ((l4 ^ ((l15 >> 1) & 3)) << 3);

    f32x4 acc[8][4] = {};
    const int nt = K >> 6;            // even, >= 4
    const int niter = nt >> 1;

    auto STAGE = [&](int tt, int kh, int isB) {
        const int c = tt & 1;
        const int k0 = (tt << 6) + (kh << 5);
        const int rbase = isB ? n0 : m0;
        const u16* P = isB ? Bt : A;
        const int ld = isB ? ldb : lda;
        const int lim = isB ? N : M;
        const int dbase = c * 32768 + isB * 16384 + kh * 8192;
        #pragma unroll
        for (int j = 0; j < 2; ++j) {
            const int r0 = j * 128 + wave * 16;
            int g = rbase + r0 + (lane >> 2); g = g < lim ? g : lim - 1;
            const u16* src = P + (long)g * ld + k0 + scol;
            __builtin_amdgcn_global_load_lds(
                (const __attribute__((address_space(1))) void*)src,
                (__attribute__((address_space(3))) void*)&lds[dbase + r0 * 32],
                16, 0, 0);
        }
    };

    bf16x8 bfr[4];
    auto LOADB = [&](int c, int kk) {
        #pragma unroll
        for (int nn = 0; nn < 4; ++nn) {
            const int row = wn * 64 + nn * 16 + l15;
            bfr[nn] = *(const bf16x8*)&lds[c * 32768 + 16384 + kk * 8192 + row * 32 + bswz];
        }
    };
    auto LDA = [&](int c, int kk, int mh, bf16x8* af) {
        #pragma unroll
        for (int mm = 0; mm < 4; ++mm) {
            const int row = wm * 128 + mh * 64 + mm * 16 + l15;
            af[mm] = *(const bf16x8*)&lds[c * 32768 + kk * 8192 + row * 32 + bswz];
        }
    };
    auto MM = [&](const bf16x8* af, int mh) {
        __builtin_amdgcn_s_setprio(1);
        #pragma unroll
        for (int mm = 0; mm < 4; ++mm)
            #pragma unroll
            for (int nn = 0; nn < 4; ++nn)
                acc[mh * 4 + mm][nn] = __builtin_amdgcn_mfma_f32_16x16x32_bf16(
                    af[mm], bfr[nn], acc[mh * 4 + mm][nn], 0, 0, 0);
        __builtin_amdgcn_s_setprio(0);
    };

    STAGE(0, 0, 0); STAGE(0, 0, 1); STAGE(0, 1, 0); STAGE(0, 1, 1);
    STAGE(1, 0, 0); STAGE(1, 0, 1);

    bf16x8 a0[4], a1[4];
    for (int i = 0; i < niter; ++i) {
        const int t0 = 2 * i, t1 = t0 + 1;
        const bool has2 = (t0 + 2 < nt);
        WAITV(8); barx();
        LOADB(0, 0); LDA(0, 0, 0, a0);
        STAGE(t1, 1, 0); STAGE(t1, 1, 1);
        MM(a0, 0); LDA(0, 0, 1, a1); MM(a1, 1);
        WAITV(8); barx();
        LOADB(0, 1); LDA(0, 1, 0, a0);
        if (has2) { STAGE(t0 + 2, 0, 0); STAGE(t0 + 2, 0, 1); }
        MM(a0, 0); LDA(0, 1, 1, a1); MM(a1, 1);
        if (has2) { WAITV(8); } else { WAITV(4); }
        barx();
        LOADB(1, 0); LDA(1, 0, 0, a0);
        if (has2) { STAGE(t0 + 2, 1, 0); STAGE(t0 + 2, 1, 1); }
        MM(a0, 0); LDA(1, 0, 1, a1); MM(a1, 1);
        if (has2) { WAITV(8); } else { WAITV(0); }
        barx();
        LOADB(1, 1); LDA(1, 1, 0, a0);
        if (has2) { STAGE(t1 + 2, 0, 0); STAGE(t1 + 2, 0, 1); }
        MM(a0, 0); LDA(1, 1, 1, a1); MM(a1, 1);
    }

    // epilogue: D map col=lane&15, row=4*(lane>>4)+reg  [m89-verified]
    #pragma unroll
    for (int mr = 0; mr < 8; ++mr) {
        #pragma unroll
        for (int nn = 0; nn < 4; ++nn) {
            const int col = n0 + wn * 64 + nn * 16 + l15;
            if (col >= N) continue;
            const float bv = bias ? bias[col] : 0.0f;
            #pragma unroll
            for (int jj = 0; jj < 4; ++jj) {
                const int row = m0 + wm * 128 + mr * 16 + l4 * 4 + jj;
                if (row >= M) continue;
                float v = alpha * acc[mr][nn][jj] + bv;
                long crow = row;
                if (row_remap) crow = (long)(row >> 6) * 129 + 65 + (row & 63);
                if (c_bf16) ((u16*)Cv)[crow * (long)ldc + col] = f2b(v);
                else        ((float*)Cv)[crow * (long)ldc + col] = v;
            }
        }
    }
}

__global__ __launch_bounds__(512, 2) void gemm_8p(
    const u16* __restrict__ A, const u16* __restrict__ Bt, void* __restrict__ Cv,
    const float* __restrict__ bias, int M, int N, int K,
    int lda, int ldb, int ldc, float alpha, int c_bf16, int row_remap)
{
    __shared__ u16 lds[65536];
    gemm8p_body(A, Bt, Cv, bias, M, N, K, lda, ldb, ldc, alpha, c_bf16, row_remap,
                blockIdx.x * 256, blockIdx.y * 256, lds);
}

// z-merged variant: per-z A/B/C/bias, bf16 outputs.
__global__ __launch_bounds__(512, 2) void gemm_8p3(
    const u16* A0, const u16* A1, const u16* A2,
    const u16* B0, const u16* B1, const u16* B2,
    u16* C0, u16* C1, u16* C2,
    const float* bias0, const float* bias1, const float* bias2,
    int M, int N, int K, int lda, int ldb, int ldc, float alpha, int row_remap)
{
    __shared__ u16 lds[65536];
    const int z = blockIdx.z;
    const u16* A = z == 0 ? A0 : (z == 1 ? A1 : A2);
    const u16* B = z == 0 ? B0 : (z == 1 ? B1 : B2);
    u16* C = z == 0 ? C0 : (z == 1 ? C1 : C2);
    const float* bias = z == 0 ? bias0 : (z == 1 ? bias1 : bias2);
    gemm8p_body(A, B, C, bias, M, N, K, lda, ldb, ldc, alpha, 1, row_remap,
                blockIdx.x * 256, blockIdx.y * 256, lds);
}

// ---------------------------------------------------------------------------
// Pipelined 128^2 bf16 GEMM (proj), persistent.
// ---------------------------------------------------------------------------
__global__ __launch_bounds__(256, 2) void gemm_pipe(
    const u16* __restrict__ A, const u16* __restrict__ Bt, void* __restrict__ Cv,
    const float* __restrict__ bias, int M, int N, int K,
    int lda, int ldb, int ldc, float alpha, int c_bf16)
{
    __shared__ u16 lds[2 * 16384];

    const int tid = threadIdx.x, lane = tid & 63, wave = tid >> 6;
    const int wm = wave >> 1, wn = wave & 1;
    const int l15 = lane & 15, l4 = lane >> 4;

    const int srow = tid >> 3;
    const int scol = (((tid & 7) * 16) ^ (((tid >> 3) & 7) << 4)) >> 1;
    const int cf0 = (((0 * 64) + l4 * 16) ^ ((l15 & 7) << 4)) >> 1;
    const int cf1 = (((1 * 64) + l4 * 16) ^ ((l15 & 7) << 4)) >> 1;

    const int nt = K >> 6;
    const int nbx = (M + 127) >> 7, nby = N >> 7;
    const int ntiles = nbx * nby;

    for (int tile = blockIdx.x; tile < ntiles; tile += gridDim.x) {
        const int m0 = (tile / nby) * 128, n0 = (tile % nby) * 128;

        auto STAGE = [&](int c, int t) {
            const int k0 = t << 6;
            #pragma unroll
            for (int j = 0; j < 4; ++j) {
                const int r = j * 32 + srow;
                int ga = m0 + r; ga = ga < M ? ga : M - 1;
                const u16* srcA = A + (long)ga * lda + k0 + scol;
                __builtin_amdgcn_global_load_lds(
                    (const __attribute__((address_space(1))) void*)srcA,
                    (__attribute__((address_space(3))) void*)&lds[c * 16384 + j * 2048 + wave * 512],
                    16, 0, 0);
                int gb = n0 + r; gb = gb < N ? gb : N - 1;
                const u16* srcB = Bt + (long)gb * ldb + k0 + scol;
                __builtin_amdgcn_global_load_lds(
                    (const __attribute__((address_space(1))) void*)srcB,
                    (__attribute__((address_space(3))) void*)&lds[c * 16384 + 8192 + j * 2048 + wave * 512],
                    16, 0, 0);
            }
        };

        f32x4 acc[4][4] = {};
        STAGE(0, 0);
        __syncthreads();
        for (int t = 0; t < nt; ++t) {
            const int c = t & 1;
            if (t + 1 < nt) STAGE(c ^ 1, t + 1);
            const int ab = c * 16384, bb = ab + 8192;
            #pragma unroll
            for (int kk = 0; kk < 2; ++kk) {
                const int cf = kk ? cf1 : cf0;
                bf16x8 af[4], bfr[4];
                #pragma unroll
                for (int m = 0; m < 4; ++m)
                    af[m] = *(const bf16x8*)&lds[ab + (wm * 64 + m * 16 + l15) * 64 + cf];
                #pragma unroll
                for (int n = 0; n < 4; ++n)
                    bfr[n] = *(const bf16x8*)&lds[bb + (wn * 64 + n * 16 + l15) * 64 + cf];
                __builtin_amdgcn_s_setprio(1);
                #pragma unroll
                for (int m = 0; m < 4; ++m)
                    #pragma unroll
                    for (int n = 0; n < 4; ++n)
                        acc[m][n] = __builtin_amdgcn_mfma_f32_16x16x32_bf16(
                            af[m], bfr[n], acc[m][n], 0, 0, 0);
                __builtin_amdgcn_s_setprio(0);
            }
            __syncthreads();
        }

        #pragma unroll
        for (int m = 0; m < 4; ++m) {
            #pragma unroll
            for (int n = 0; n < 4; ++n) {
                const int col = n0 + wn * 64 + n * 16 + l15;
                if (col >= N) continue;
                const float bv = bias ? bias[col] : 0.0f;
                #pragma unroll
                for (int j = 0; j < 4; ++j) {
                    const int row = m0 + wm * 64 + m * 16 + l4 * 4 + j;
                    if (row >= M) continue;
                    float v = alpha * acc[m][n][j] + bv;
                    if (c_bf16) ((u16*)Cv)[(long)row * ldc + col] = f2b(v);
                    else        ((float*)Cv)[(long)row * ldc + col] = v;
                }
            }
        }
    }
}

// ---------------------------------------------------------------------------
// Generic bf16 GEMM (batch): attn@v (batched K=144, M=128).
// ---------------------------------------------------------------------------
__global__ __launch_bounds__(256) void gemm_bt(
    const u16* __restrict__ A, const u16* __restrict__ Bt, void* __restrict__ Cv,
    const float* __restrict__ bias, int M, int N, int K,
    int lda, int ldb, int ldc, float alpha, int c_bf16, int row_remap,
    long sA, long sB, long sCo, long sCi, int binner)
{
    const int bz = blockIdx.z;
    const u16* Ab = A + (long)bz * sA;
    const u16* Bb = Bt + (long)bz * sB;
    const long cOff = (long)(bz / binner) * sCo + (long)(bz % binner) * sCi;

    __shared__ u16 As[128][72];
    __shared__ u16 Bs[128][72];

    const int tid = threadIdx.x;
    const int lane = tid & 63;
    const int wave = tid >> 6;
    const int wr = wave >> 1, wc = wave & 1;
    const int l15 = lane & 15, l4 = lane >> 4;
    const int m0 = blockIdx.x * 128, n0 = blockIdx.y * 128;

    const int r = tid >> 3;
    const int kof = (tid & 7) * 8;

    f32x4 acc[4][4] = {};

    const int ktiles = (K + 63) / 64;
    for (int kt = 0; kt < ktiles; ++kt) {
        const int k0 = kt * 64;
        __syncthreads();
        #pragma unroll
        for (int i = 0; i < 4; ++i) {
            const int row = r + 32 * i;
            const int gk = k0 + kof;
            u16x8 v = {0,0,0,0,0,0,0,0};
            const int grow = m0 + row;
            if (grow < M && gk < K)
                v = *(const u16x8*)(Ab + (long)grow * lda + gk);
            *(u16x8*)&As[row][kof] = v;
        }
        #pragma unroll
        for (int i = 0; i < 4; ++i) {
            const int row = r + 32 * i;
            const int gk = k0 + kof;
            u16x8 v = {0,0,0,0,0,0,0,0};
            const int gcol = n0 + row;
            if (gcol < N && gk < K)
                v = *(const u16x8*)(Bb + (long)gcol * ldb + gk);
            *(u16x8*)&Bs[row][kof] = v;
        }
        __syncthreads();
        #pragma unroll
        for (int ks = 0; ks < 2; ++ks) {
            bf16x8 af[4], bfr[4];
            #pragma unroll
            for (int m = 0; m < 4; ++m)
                af[m] = *(const bf16x8*)&As[wr*64 + m*16 + l15][ks*32 + l4*8];
            #pragma unroll
            for (int n = 0; n < 4; ++n)
                bfr[n] = *(const bf16x8*)&Bs[wc*64 + n*16 + l15][ks*32 + l4*8];
            #pragma unroll
            for (int m = 0; m < 4; ++m)
                #pragma unroll
                for (int n = 0; n < 4; ++n)
                    acc[m][n] = __builtin_amdgcn_mfma_f32_16x16x32_bf16(
                        af[m], bfr[n], acc[m][n], 0, 0, 0);
        }
    }

    #pragma unroll
    for (int m = 0; m < 4; ++m) {
        #pragma unroll
        for (int n = 0; n < 4; ++n) {
            const int col = n0 + wc*64 + n*16 + l15;
            if (col >= N) continue;
            const float bv = bias ? bias[col] : 0.0f;
            #pragma unroll
            for (int j = 0; j < 4; ++j) {
                const int row = m0 + wr*64 + m*16 + l4*4 + j;
                if (row >= M) continue;
                float v = alpha * acc[m][n][j] + bv;
                long crow = row;
                if (row_remap) crow = (long)(row >> 6) * 129 + 65 + (row & 63);
                if (c_bf16) ((u16*)Cv)[cOff + crow * (long)ldc + col] = f2b(v);
                else        ((float*)Cv)[cOff + crow * (long)ldc + col] = v;
            }
        }
    }
}

// ---------------------------------------------------------------------------
// Fused dots + softmax, persistent over 516 row-groups (grid 512).
// ---------------------------------------------------------------------------
__global__ __launch_bounds__(256, 2) void fdots_kernel(
    const u16* __restrict__ z, const u16* __restrict__ Wm_t,
    const float* __restrict__ bm, u16* __restrict__ attn)
{
    __shared__ u16 wlds[144 * 264];
    const int tid = threadIdx.x;
    for (int i = tid; i < 144 * 32; i += 256) {
        const int row = i >> 5, c8 = i & 31;
        *(u16x8*)&wlds[row * 264 + c8 * 8] = *(const u16x8*)&Wm_t[row * 256 + c8 * 8];
    }
    __syncthreads();
    const int lane = tid & 63, wave = tid >> 6;
    const int l15 = lane & 15, l4 = lane >> 4;

    float bmv[9];
    #pragma unroll
    for (int c = 0; c < 9; ++c) {
        const int col = c * 16 + l15;
        bmv[c] = (col < 129) ? bm[col] : 0.0f;
    }

    for (int rg = blockIdx.x; rg < 516; rg += gridDim.x) {
        const long rowbase = (long)rg * 128 + wave * 32;

        f32x4 acc[2][9] = {};
        #pragma unroll
        for (int kk = 0; kk < 8; ++kk) {
            bf16x8 af[2];
            #pragma unroll
            for (int rgp = 0; rgp < 2; ++rgp)
                af[rgp] = *(const bf16x8*)&z[(rowbase + rgp * 16 + l15) * 256 + kk * 32 + l4 * 8];
            #pragma unroll
            for (int c = 0; c < 9; ++c) {
                const bf16x8 bf = *(const bf16x8*)&wlds[(c * 16 + l15) * 264 + kk * 32 + l4 * 8];
                #pragma unroll
                for (int rgp = 0; rgp < 2; ++rgp)
                    acc[rgp][c] = __builtin_amdgcn_mfma_f32_16x16x32_bf16(af[rgp], bf, acc[rgp][c], 0, 0, 0);
            }
        }

        #pragma unroll
        for (int rgp = 0; rgp < 2; ++rgp) {
            #pragma unroll
            for (int j = 0; j < 4; ++j) {
                float v[9]; float mx = -1e30f;
                #pragma unroll
                for (int c = 0; c < 9; ++c) {
                    const int col = c * 16 + l15;
                    v[c] = (col < 129) ? (0.0625f * acc[rgp][c][j] + bmv[c]) : -1e30f;
                    mx = fmaxf(mx, v[c]);
                }
                #pragma unroll
                for (int o = 1; o < 16; o <<= 1) mx = fmaxf(mx, __shfl_xor(mx, o, 64));
                float s = 0.f;
                #pragma unroll
                for (int c = 0; c < 9; ++c) {
                    v[c] = (c * 16 + l15 < 129) ? expf(v[c] - mx) : 0.0f;
                    s += v[c];
                }
                #pragma unroll
                for (int o = 1; o < 16; o <<= 1) s += __shfl_xor(s, o, 64);
                const float inv = 1.0f / s;
                u16* ar = attn + (rowbase + rgp * 16 + l4 * 4 + j) * 144;
                #pragma unroll
                for (int c = 0; c < 9; ++c)
                    ar[c * 16 + l15] = f2b(v[c] * inv);
            }
        }
    }
}

// out row n=128 per (b,h)
__global__ __launch_bounds__(256) void row128_kernel(
    const u16* __restrict__ attn, const u16* __restrict__ v_t, u16* __restrict__ outm)
{
    const int bh = blockIdx.x, d = threadIdx.x;
    const int b = bh >> 3, h = bh & 7;
    __shared__ float a[144];
    for (int j = threadIdx.x; j < 144; j += 256)
        a[j] = (j < 129) ? b2f(attn[((long)bh * 129 + 128) * 144 + j]) : 0.0f;
    __syncthreads();
    const u16* vr = v_t + ((long)bh * 256 + d) * 144;
    float s = 0.f;
    #pragma unroll
    for (int j8 = 0; j8 < 18; ++j8) {
        const bf16x8 vv = *(const bf16x8*)&vr[j8 * 8];
        #pragma unroll
        for (int e = 0; e < 8; ++e) s += a[j8 * 8 + e] * b2f((u16)vv[e]);
    }
    outm[((long)(b * 129 + 128)) * 2048 + h * 256 + d] = f2b(s);
}

// transpose + f32->bf16, z-selectable inputs (4-way)
__global__ __launch_bounds__(256) void transpose_conv4(
    const float* in0, const float* in1, const float* in2, const float* in3,
    u16* o0, u16* o1, u16* o2, u16* o3, int K, int N, int KP, int NPd)
{
    const int zz = blockIdx.z;
    const float* in = zz == 0 ? in0 : (zz == 1 ? in1 : (zz == 2 ? in2 : in3));
    u16* out = zz == 0 ? o0 : (zz == 1 ? o1 : (zz == 2 ? o2 : o3));
    __shared__ float tile[32][33];
    const int k0 = blockIdx.x * 32, n0 = blockIdx.y * 32;
    const int tx = threadIdx.x, ty = threadIdx.y;   // (32,8)
    #pragma unroll
    for (int i = 0; i < 4; ++i) {
        const int k = k0 + ty + i*8, n = n0 + tx;
        tile[ty + i*8][tx] = (k < K && n < N) ? in[(long)k * N + n] : 0.0f;
    }
    __syncthreads();
    #pragma unroll
    for (int i = 0; i < 4; ++i) {
        const int n = n0 + ty + i*8, k = k0 + tx;
        if (n < NPd && k < KP) out[(long)n * KP + k] = f2b(tile[tx][ty + i*8]);
    }
}

// patchify, z in [0,128): b = z&63, input = z>>6.
__global__ __launch_bounds__(256) void patchify_kernel(
    const float* __restrict__ xq, const float* __restrict__ xkv,
    u16* __restrict__ oq, u16* __restrict__ okv)
{
    __shared__ u16 tile[64 * 7 * 58];
    const int zz = blockIdx.z;
    const float* x = (zz >= 64) ? xkv : xq;
    u16* out = (zz >= 64) ? okv : oq;
    const int b = zz & 63, hh = blockIdx.y, cg = blockIdx.x;
    const int c0 = cg * 64;
    for (int i = threadIdx.x; i < 64 * 392; i += 256) {
        const int c = i / 392, rem = i - c * 392;
        const int p1 = rem / 56, w = rem - p1 * 56;
        const float v = x[(((long)b * 128 + c0 + c) * 56 + hh * 7 + p1) * 56 + w];
        tile[(c * 7 + p1) * 58 + w] = f2b(v);
    }
    __syncthreads();
    #pragma unroll
    for (int ww = 0; ww < 8; ++ww) {
        const long base = ((long)(b * 64 + hh * 8 + ww)) * 6272 + c0;
        for (int j = threadIdx.x; j < 49 * 64; j += 256) {
            const int c = j & 63, pp = j >> 6;
            const int p1 = pp / 7, p2 = pp - p1 * 7;
            out[base + pp * 128 + c] = tile[(c * 7 + p1) * 58 + ww * 7 + p2];
        }
    }
}

// pos rows: grid (65, 64), thread handles 8 cols (u16x8 stores)
__global__ __launch_bounds__(256) void posfill_kernel(
    const float* __restrict__ pos, u16* __restrict__ Tq, u16* __restrict__ Tk)
{
    const int t = blockIdx.x, b = blockIdx.y;
    const int c0 = threadIdx.x * 8;
    const float* pr = pos + (long)t * 2048 + c0;
    u16x8 v;
    #pragma unroll
    for (int e = 0; e < 8; ++e) v[e] = f2b(pr[e]);
    const long idx = ((long)b * 129 + t) * 2048 + c0;
    *(u16x8*)&Tq[idx] = v;
    *(u16x8*)&Tk[idx] = v;
}

// v_t[bh][d][n (pad 144)] = vmat[(b*129+n)*2048 + h*256 + d]; pads zeroed
__global__ void vtrans_kernel(const u16* __restrict__ vmat, u16* __restrict__ v_t)
{
    const int bh = blockIdx.z; const int b = bh >> 3, h = bh & 7;
    const int d0 = blockIdx.x * 32, n0 = blockIdx.y * 32;
    __shared__ u16 tile[32][33];
    const int tx = threadIdx.x, ty = threadIdx.y;   // (32,8)
    #pragma unroll
    for (int i = 0; i < 4; ++i) {
        const int n = n0 + ty + i*8;
        if (n < 129)
            tile[ty + i*8][tx] = vmat[((long)b*129 + n) * 2048 + h*256 + d0 + tx];
    }
    __syncthreads();
    #pragma unroll
    for (int i = 0; i < 4; ++i) {
        const int d = d0 + ty + i*8, n = n0 + tx;
        if (n < 144)
            v_t[((long)bh * 256 + d) * 144 + n] = (n < 129) ? tile[tx][ty + i*8] : (u16)0;
    }
}

// --------------------- threefry2x32, partitionable path --------------------
static __device__ __forceinline__ unsigned int rotl32(unsigned int x, int d) {
    return (x << d) | (x >> (32 - d));
}

static __device__ __forceinline__ float threefry_normal(unsigned int i) {
    const unsigned int ks0 = 0u, ks1 = 42u;
    const unsigned int ks2 = ks0 ^ ks1 ^ 0x1BD11BDAu;
    unsigned int x0 = 0u + ks0;
    unsigned int x1 = i + ks1;
#define TF_R(rr) { x0 += x1; x1 = rotl32(x1, rr); x1 ^= x0; }
    TF_R(13) TF_R(15) TF_R(26) TF_R(6)
    x0 += ks1; x1 += ks2 + 1u;
    TF_R(17) TF_R(29) TF_R(16) TF_R(24)
    x0 += ks2; x1 += ks0 + 2u;
    TF_R(13) TF_R(15) TF_R(26) TF_R(6)
    x0 += ks0; x1 += ks1 + 3u;
    TF_R(17) TF_R(29) TF_R(16) TF_R(24)
    x0 += ks1; x1 += ks2 + 4u;
    TF_R(13) TF_R(15) TF_R(26) TF_R(6)
    x0 += ks2; x1 += ks0 + 5u;
#undef TF_R
    const unsigned int bits = x0 ^ x1;
    const unsigned int fb = (bits >> 9) | 0x3f800000u;
    union { unsigned int u; float f; } cv; cv.u = fb;
    const float f = cv.f - 1.0f;
    const float lo = -0.99999994f;
    float u = f * (1.0f - lo) + lo;
    u = fmaxf(lo, u);
    return 1.4142135623730951f * erfinvf(u);
}

// fused: z = k + exp(0.5 q) * eps (bf16), outq = q/||q||, outk = k/||k||.
__global__ __launch_bounds__(256) void z_kernel(
    const u16* __restrict__ qmat, const u16* __restrict__ kmat,
    const float* __restrict__ norms, u16* __restrict__ z,
    float* __restrict__ outq, float* __restrict__ outk)
{
    const unsigned int i = blockIdx.x * 256u + threadIdx.x;
    const int d = i & 255; const unsigned int t = i >> 8;
    const int n = t % 129; const int bh = t / 129;
    const int b = bh >> 3, h = bh & 7;
    const long src = ((long)(b * 129 + n)) * 2048 + h * 256 + d;
    const float qf = b2f(qmat[src]);
    const float kf = b2f(kmat[src]);
    const float eps = threefry_normal(i);
    z[i] = f2b(kf + expf(0.5f * qf) * eps);
    outq[i] = qf / norms[b];
    outk[i] = kf / norms[64 + b];
}

// LayerNorm row of proj[8256][2048] (bf16) -> ln bf16
__global__ __launch_bounds__(256) void ln_kernel(
    const u16* __restrict__ proj, const float* __restrict__ gamma,
    const float* __restrict__ beta, u16* __restrict__ ln)
{
    const int row = blockIdx.x;
    const u16* p = proj + (long)row * 2048;
    const int tid = threadIdx.x;
    float v[8]; float s = 0.f, s2 = 0.f;
    #pragma unroll
    for (int i = 0; i < 8; ++i) {
        v[i] = b2f(p[tid + i * 256]); s += v[i]; s2 += v[i] * v[i];
    }
    #pragma unroll
    for (int o = 32; o > 0; o >>= 1) { s += __shfl_down(s, o, 64); s2 += __shfl_down(s2, o, 64); }
    __shared__ float sh[8];
    if ((tid & 63) == 0) { sh[tid >> 6] = s; sh[4 + (tid >> 6)] = s2; }
    __syncthreads();
    s = sh[0] + sh[1] + sh[2] + sh[3];
    s2 = sh[4] + sh[5] + sh[6] + sh[7];
    const float mu = s * (1.0f / 2048.0f);
    const float var = s2 * (1.0f / 2048.0f) - mu * mu;
    const float rinv = 1.0f / sqrtf(var + 1e-5f);
    u16* lr = ln + (long)row * 2048;
    #pragma unroll
    for (int i = 0; i < 8; ++i) {
        const int c = tid + i * 256;
        lr[c] = f2b((v[i] - mu) * rinv * gamma[c] + beta[c]);
    }
}

// ---------------------------------------------------------------------------
// Two-stage L2 norms, deterministic (no atomics).
// ---------------------------------------------------------------------------
__global__ __launch_bounds__(256) void norm_partial(
    const u16* __restrict__ qmat, const u16* __restrict__ kmat,
    float* __restrict__ part)
{
    const int blk = blockIdx.x;               // 0..2047
    const int p = blk >> 4, sub = blk & 15;   // p: 0..127 (q:0-63, k:64-127)
    const int b = p & 63;
    const u16* src = (p >= 64 ? kmat : qmat) + (long)b * 264192 + sub * 16512;
    float s = 0.f;
    for (int i = threadIdx.x; i < 2064; i += 256) {       // 2064 x 8 = 16512
        const bf16x8 v = *(const bf16x8*)&src[i * 8];
        #pragma unroll
        for (int e = 0; e < 8; ++e) { const float x = b2f((u16)v[e]); s += x * x; }
    }
    #pragma unroll
    for (int o = 32; o > 0; o >>= 1) s += __shfl_down(s, o, 64);
    __shared__ float sh[4];
    if ((threadIdx.x & 63) == 0) sh[threadIdx.x >> 6] = s;
    __syncthreads();
    if (threadIdx.x == 0) part[blk] = sh[0] + sh[1] + sh[2] + sh[3];
}

__global__ void norm_final(const float* __restrict__ part, float* __restrict__ norms)
{
    const int p = threadIdx.x;                // 128 threads
    float s = 0.f;
    #pragma unroll
    for (int j = 0; j < 16; ++j) s += part[p * 16 + j];
    norms[p] = sqrtf(s);
}

// ---------------------------------------------------------------------------
extern "C" void kernel_launch(void* const* d_in, const int* in_sizes, int n_in,
                              void* d_out, int out_size, void* d_ws, size_t ws_size,
                              hipStream_t stream)
{
    const float* x_q   = (const float*)d_in[0];
    const float* x_kv  = (const float*)d_in[1];
    const float* W_ex  = (const float*)d_in[2];
    const float* b_ex  = (const float*)d_in[3];
    const float* W_en  = (const float*)d_in[4];
    const float* b_en  = (const float*)d_in[5];
    const float* pos   = (const float*)d_in[6];
    const float* Wq    = (const float*)d_in[7];
    const float* Wk    = (const float*)d_in[8];
    const float* Wv    = (const float*)d_in[9];
    const float* Wo    = (const float*)d_in[10];
    const float* bo    = (const float*)d_in[11];
    const float* gamma = (const float*)d_in[12];
    const float* beta  = (const float*)d_in[13];
    const float* Wh    = (const float*)d_in[14];
    const float* bh    = (const float*)d_in[15];
    const float* Wm    = (const float*)d_in[16];
    const float* bm    = (const float*)d_in[17];
    (void)in_sizes; (void)n_in; (void)out_size; (void)ws_size;

    char* ws = (char*)d_ws;
    size_t off = 0;
    auto alloc = [&](size_t bytes) -> char* {
        char* p = ws + off;
        off += (bytes + 255) & ~(size_t)255;
        return p;
    };
    u16*   Xq_p  = (u16*)alloc(4096UL * 6272 * 2);
    u16*   Xk_p  = (u16*)alloc(4096UL * 6272 * 2);
    u16*   Wex_t = (u16*)alloc(2048UL * 6272 * 2);
    u16*   Wen_t = (u16*)alloc(2048UL * 6272 * 2);
    u16*   Tq    = (u16*)alloc(8256UL * 2048 * 2);
    u16*   Tk    = (u16*)alloc(8256UL * 2048 * 2);
    u16*   Wq_t  = (u16*)alloc(2048UL * 2048 * 2);
    u16*   Wk_t  = (u16*)alloc(2048UL * 2048 * 2);
    u16*   Wv_t  = (u16*)alloc(2048UL * 2048 * 2);
    u16*   qmat  = (u16*)alloc(8256UL * 2048 * 2);
    u16*   kmat  = (u16*)alloc(8256UL * 2048 * 2);
    u16*   vmat  = (u16*)alloc(8256UL * 2048 * 2);
    u16*   v_t   = (u16*)alloc(512UL * 256 * 144 * 2);
    u16*   z     = (u16*)alloc(66048UL * 256 * 2);
    u16*   attn  = (u16*)alloc(66048UL * 144 * 2);
    u16*   outm  = (u16*)alloc(8256UL * 2048 * 2);
    u16*   proj  = (u16*)alloc(8256UL * 2048 * 2);
    u16*   ln    = (u16*)alloc(8256UL * 2048 * 2);
    u16*   Wo_t  = (u16*)alloc(2048UL * 2048 * 2);
    u16*   Wh_t  = (u16*)alloc(6272UL * 2048 * 2);
    u16*   Wm_t  = (u16*)alloc(144UL * 256 * 2);
    float* norms = (float*)alloc(128UL * 4);
    float* part  = (float*)alloc(2048UL * 4);

    // s1: transposes (merged) + patchify (merged) + pos tokens
    transpose_conv4<<<dim3(196, 64, 2), dim3(32, 8), 0, stream>>>(
        W_ex, W_en, W_ex, W_en, Wex_t, Wen_t, Wex_t, Wen_t, 6272, 2048, 6272, 2048);
    patchify_kernel<<<dim3(2, 8, 128), 256, 0, stream>>>(x_q, x_kv, Xq_p, Xk_p);
    posfill_kernel<<<dim3(65, 64), 256, 0, stream>>>(pos, Tq, Tk);

    // s2: merged embed GEMMs (z=2): 256 blocks
    gemm_8p3<<<dim3(16, 8, 2), 512, 0, stream>>>(
        Xq_p, Xk_p, Xk_p, Wex_t, Wen_t, Wen_t, Tq, Tk, Tk,
        b_ex, b_en, b_en, 4096, 2048, 6272, 6272, 6272, 2048, 1.0f, 1);

    // s3: QKV+Wo transposes (z=4) + merged QKV GEMM (z=3, bf16)
    transpose_conv4<<<dim3(64, 64, 4), dim3(32, 8), 0, stream>>>(
        Wq, Wk, Wv, Wo, Wq_t, Wk_t, Wv_t, Wo_t, 2048, 2048, 2048, 2048);
    gemm_8p3<<<dim3(33, 8, 3), 512, 0, stream>>>(
        Tq, Tk, Tk, Wq_t, Wk_t, Wv_t, qmat, kmat, vmat,
        nullptr, nullptr, nullptr, 8256, 2048, 2048, 2048, 2048, 2048, 1.0f, 0);

    // s4: v transpose -> v_t [bh][d][n pad144]
    vtrans_kernel<<<dim3(8, 5, 512), dim3(32, 8), 0, stream>>>(vmat, v_t);

    // s5: two-stage norms then fused reparam + qn/kn outputs
    norm_partial<<<2048, 256, 0, stream>>>(qmat, kmat, part);
    norm_final<<<1, 128, 0, stream>>>(part, norms);
    {
        float* outq = (float*)d_out + 51781632L;
        float* outk = outq + 16908288L;
        z_kernel<<<66048, 256, 0, stream>>>(qmat, kmat, norms, z, outq, outk);
    }

    // s6: Wm^T, fused dots+softmax -> attn bf16 (persistent, 512 blocks)
    transpose_conv4<<<dim3(8, 5, 1), dim3(32, 8), 0, stream>>>(
        Wm, Wm, Wm, Wm, Wm_t, Wm_t, Wm_t, Wm_t, 256, 129, 256, 144);
    fdots_kernel<<<512, 256, 0, stream>>>(z, Wm_t, bm, attn);

    // s7: attn @ v (batched bh=512, M=128) + row-128 kernel
    {
        dim3 grid(1, 2, 512);
        gemm_bt<<<grid, 256, 0, stream>>>(attn, v_t, outm, nullptr,
            128, 256, 144, 144, 144, 2048, 1.0f, 1, 0,
            129L * 144, 256L * 144, 129L * 2048, 256L, 8);
    }
    row128_kernel<<<512, 256, 0, stream>>>(attn, v_t, outm);

    // s8: proj GEMM (persistent gemm_pipe, bf16 out)
    gemm_pipe<<<1024, 256, 0, stream>>>(
        outm, Wo_t, proj, bo, 8256, 2048, 2048, 2048, 2048, 2048, 1.0f, 1);

    // s9: LayerNorm (bf16 in) -> ln bf16
    ln_kernel<<<8256, 256, 0, stream>>>(proj, gamma, beta, ln);

    // s10: Wh^T, head GEMM (8p) -> d_out[0 : 51,781,632] f32
    transpose_conv4<<<dim3(64, 196, 1), dim3(32, 8), 0, stream>>>(
        Wh, Wh, Wh, Wh, Wh_t, Wh_t, Wh_t, Wh_t, 2048, 6272, 2048, 6272);
    gemm_8p<<<dim3(33, 25), 512, 0, stream>>>(
        ln, Wh_t, (float*)d_out, bh, 8256, 6272, 2048, 2048, 2048, 6272, 1.0f, 0, 0);
}